// Round 1
// baseline (233.796 us; speedup 1.0000x reference)
//
#include <hip/hip_runtime.h>
#include <math.h>

// Problem constants: cost [8,1,48,128,240] f32, spg [8,9,512,960] f32
#define BB 8
#define DD 48
#define HH 128
#define WW 240
#define HW (HH * WW)
#define FH (4 * HH)   // 512
#define FW (4 * WW)   // 960
#define FHW (FH * FW)

typedef float vf4 __attribute__((ext_vector_type(4)));

// Stage 1: top-2 along D + softmax-of-2 weighted index -> disp4 [b,h,w]
// One thread per 4 consecutive w pixels (vf4 = 16 B/lane loads), 240 blocks
// -> exactly 1 block on ~94% of CUs, perfectly balanced tail.
// 16-deep double-buffered load pipeline: >=16 vf4 loads in flight while the
// previous batch is consumed (batch compute ~1024 cyc > ~900 cyc HBM latency).
__global__ __launch_bounds__(256, 1) void disp4_kernel(const float* __restrict__ cost,
                                                       float* __restrict__ disp4) {
    int t = blockIdx.x * blockDim.x + threadIdx.x;
    const int WQ = WW / 4;                 // 60
    if (t >= BB * HH * WQ) return;
    int wq = t % WQ;
    int r  = t / WQ;
    int hy = r % HH;
    int b  = r / HH;

    const float* base = cost + (size_t)b * DD * HW + (size_t)hy * WW + wq * 4;

    float m1[4], m2[4], i1[4], i2[4];
#pragma unroll
    for (int k = 0; k < 4; ++k) { m1[k] = -INFINITY; m2[k] = -INFINITY; i1[k] = 0.f; i2[k] = 0.f; }

    vf4 A[16], B[16];

    auto load16 = [&](vf4* buf, int d0) {
#pragma unroll
        for (int u = 0; u < 16; ++u)
            buf[u] = __builtin_nontemporal_load(
                reinterpret_cast<const vf4*>(base + (size_t)(d0 + u) * HW));
    };
    auto proc16 = [&](const vf4* buf, int d0) {
#pragma unroll
        for (int u = 0; u < 16; ++u) {
            float fd = (float)(d0 + u);
#pragma unroll
            for (int k = 0; k < 4; ++k) {
                float vv = buf[u][k];
                // strict > keeps lower index on ties (matches jax.lax.top_k)
                bool g1 = vv > m1[k];
                bool g2 = vv > m2[k];
                m2[k] = g1 ? m1[k] : (g2 ? vv : m2[k]);
                i2[k] = g1 ? i1[k] : (g2 ? fd : i2[k]);
                m1[k] = g1 ? vv : m1[k];
                i1[k] = g1 ? fd : i1[k];
            }
        }
    };

    load16(A, 0);      // batches 0..15 in flight
    load16(B, 16);     // batches 16..31 in flight
    proc16(A, 0);
    load16(A, 32);     // 32..47 in flight while B is consumed
    proc16(B, 16);
    proc16(A, 32);

    vf4 o;
#pragma unroll
    for (int k = 0; k < 4; ++k) {
        float e = __expf(m2[k] - m1[k]);   // e <= 1 since m1 >= m2
        float s = e / (1.f + e);
        o[k] = i1[k] + (i2[k] - i1[k]) * s;
    }
    // plain (cached) store: disp4 is re-read by upfeat_kernel immediately
    *reinterpret_cast<vf4*>(disp4 + (size_t)b * HW + (size_t)hy * WW + wq * 4) = o;
}

// Stage 2: softmax over 9 spg channels, weighted sum of 3x3 disp4 patch
// (nearest-4x-upsampled), *4. One thread per 8 consecutive output x:
// one shared 3x4 coarse patch (12 gathers for 2 quads instead of 18),
// half the address arithmetic, 3840 perfectly balanced 128-thread blocks.
__global__ __launch_bounds__(128) void upfeat_kernel(const float* __restrict__ spg,
                                                     const float* __restrict__ disp4,
                                                     float* __restrict__ out) {
    int t = blockIdx.x * blockDim.x + threadIdx.x;
    const int XO = FW / 8;                 // 120
    if (t >= BB * FH * XO) return;
    int xo = t % XO;                       // octet index: fine x = xo*8 .. xo*8+7
    int r  = t / XO;
    int y  = r % FH;
    int b  = r / FH;
    int hy = y >> 2;
    int cx0 = xo * 2 - 1;                  // leftmost coarse col of the 3x4 patch

    // 3x4 patch of disp4, zero-padded (heavily reused across threads -> L1/L2)
    float p[3][4];
#pragma unroll
    for (int i = 0; i < 3; ++i) {
        int cy = hy + i - 1;
        bool oky = (cy >= 0) & (cy < HH);
#pragma unroll
        for (int j = 0; j < 4; ++j) {
            int cx = cx0 + j;
            bool ok = oky & (cx >= 0) & (cx < WW);
            p[i][j] = ok ? disp4[(size_t)b * HW + (size_t)cy * WW + cx] : 0.f;
        }
    }

    const float* sp = spg + ((size_t)b * 9 * FH + (size_t)y) * FW + xo * 8;
    vf4 s0[9], s1[9];
#pragma unroll
    for (int c = 0; c < 9; ++c) {
        s0[c] = __builtin_nontemporal_load(reinterpret_cast<const vf4*>(sp + (size_t)c * FHW));
        s1[c] = __builtin_nontemporal_load(reinterpret_cast<const vf4*>(sp + (size_t)c * FHW + 4));
    }

    vf4 ov[2];
#pragma unroll
    for (int q = 0; q < 2; ++q) {          // q = quad within the octet (coarse col cx0+1+q)
        const vf4* sv = q ? s1 : s0;
#pragma unroll
        for (int k = 0; k < 4; ++k) {
            float m = sv[0][k];
#pragma unroll
            for (int c = 1; c < 9; ++c) m = fmaxf(m, sv[c][k]);
            float num = 0.f, den = 0.f;
#pragma unroll
            for (int c = 0; c < 9; ++c) {
                float e = __expf(sv[c][k] - m);
                // channel c = ki*3+kj (unfold row-major); patch col = q + kj
                num = fmaf(e, p[c / 3][q + c % 3], num);
                den += e;
            }
            ov[q][k] = 4.f * __fdividef(num, den);
        }
    }

    float* ob = out + ((size_t)b * FH + (size_t)y) * FW + xo * 8;
    __builtin_nontemporal_store(ov[0], reinterpret_cast<vf4*>(ob));
    __builtin_nontemporal_store(ov[1], reinterpret_cast<vf4*>(ob + 4));
}

extern "C" void kernel_launch(void* const* d_in, const int* in_sizes, int n_in,
                              void* d_out, int out_size, void* d_ws, size_t ws_size,
                              hipStream_t stream) {
    const float* cost = (const float*)d_in[0];
    const float* spg  = (const float*)d_in[1];
    float* outp  = (float*)d_out;
    float* disp4 = (float*)d_ws;           // needs BB*HH*WW*4 = 3.93 MB

    {
        int total = BB * HH * (WW / 4);    // 61440
        int blocks = (total + 255) / 256;  // 240 -> 1 block per CU on 240/256 CUs
        disp4_kernel<<<blocks, 256, 0, stream>>>(cost, disp4);
    }
    {
        int total = BB * FH * (FW / 8);    // 491520
        int blocks = (total + 127) / 128;  // 3840 -> exactly 15 blocks/CU
        upfeat_kernel<<<blocks, 128, 0, stream>>>(spg, disp4, outp);
    }
}

// Round 2
// 222.751 us; speedup vs baseline: 1.0496x; 1.0496x over previous
//
#include <hip/hip_runtime.h>
#include <math.h>

// Problem constants: cost [8,1,48,128,240] f32, spg [8,9,512,960] f32
#define BB 8
#define DD 48
#define HH 128
#define WW 240
#define HW (HH * WW)
#define FH (4 * HH)   // 512
#define FW (4 * WW)   // 960
#define FHW (FH * FW)

typedef float vf2 __attribute__((ext_vector_type(2)));
typedef float vf4 __attribute__((ext_vector_type(4)));

// Stage 1: top-2 along D + softmax-of-2 weighted index -> disp4 [b,h,w]
// One thread per 4 consecutive w pixels (vf4 = 16 B/lane, 1 KiB/wave-instr),
// 240 blocks -> 1 block/CU, perfectly balanced. 16-deep double-buffered load
// pipeline keeps >=16 vf4 loads in flight (64 KB/CU) while computing.
__global__ __launch_bounds__(256, 1) void disp4_kernel(const float* __restrict__ cost,
                                                       float* __restrict__ disp4) {
    int t = blockIdx.x * blockDim.x + threadIdx.x;
    const int WQ = WW / 4;                 // 60
    if (t >= BB * HH * WQ) return;
    int wq = t % WQ;
    int r  = t / WQ;
    int hy = r % HH;
    int b  = r / HH;

    const float* base = cost + (size_t)b * DD * HW + (size_t)hy * WW + wq * 4;

    float m1[4], m2[4], i1[4], i2[4];
#pragma unroll
    for (int k = 0; k < 4; ++k) { m1[k] = -INFINITY; m2[k] = -INFINITY; i1[k] = 0.f; i2[k] = 0.f; }

    vf4 A[16], B[16];

    auto load16 = [&](vf4* buf, int d0) {
#pragma unroll
        for (int u = 0; u < 16; ++u)
            buf[u] = __builtin_nontemporal_load(
                reinterpret_cast<const vf4*>(base + (size_t)(d0 + u) * HW));
    };
    auto proc16 = [&](const vf4* buf, int d0) {
#pragma unroll
        for (int u = 0; u < 16; ++u) {
            float fd = (float)(d0 + u);
#pragma unroll
            for (int k = 0; k < 4; ++k) {
                float vv = buf[u][k];
                // strict > keeps lower index on ties (matches jax.lax.top_k)
                bool g1 = vv > m1[k];
                bool g2 = vv > m2[k];
                m2[k] = g1 ? m1[k] : (g2 ? vv : m2[k]);
                i2[k] = g1 ? i1[k] : (g2 ? fd : i2[k]);
                m1[k] = g1 ? vv : m1[k];
                i1[k] = g1 ? fd : i1[k];
            }
        }
    };

    load16(A, 0);      // batches 0..15 in flight
    load16(B, 16);     // batches 16..31 in flight
    proc16(A, 0);
    load16(A, 32);     // 32..47 in flight while B is consumed
    proc16(B, 16);
    proc16(A, 32);

    vf4 o;
#pragma unroll
    for (int k = 0; k < 4; ++k) {
        float e = __expf(m2[k] - m1[k]);   // e <= 1 since m1 >= m2
        float s = e / (1.f + e);
        o[k] = i1[k] + (i2[k] - i1[k]) * s;
    }
    // plain (cached) store: disp4 is re-read by upfeat_kernel immediately
    *reinterpret_cast<vf4*>(disp4 + (size_t)b * HW + (size_t)hy * WW + wq * 4) = o;
}

// Stage 2 (reverted to round-0 baseline): softmax over 9 spg channels,
// weighted sum of 3x3 disp4 patch (nearest-4x-upsampled), *4.
// One thread per 4 consecutive output x -> 16 B/lane stride-free coalescing
// on every spg load (the 8-px variant's 32 B lane stride regressed -13 us).
__global__ __launch_bounds__(256) void upfeat_kernel(const float* __restrict__ spg,
                                                     const float* __restrict__ disp4,
                                                     float* __restrict__ out) {
    int t = blockIdx.x * blockDim.x + threadIdx.x;
    const int XQ = FW / 4;                 // 240
    if (t >= BB * FH * XQ) return;
    int xq = t % XQ;                       // coarse x == fine x / 4
    int r  = t / XQ;
    int y  = r % FH;
    int b  = r / FH;
    int hy = y >> 2;

    // 3x3 patch of disp4, zero-padded (heavily reused across threads -> L1/L2)
    float p[9];
#pragma unroll
    for (int i = 0; i < 3; ++i) {
#pragma unroll
        for (int j = 0; j < 3; ++j) {
            int cy = hy + i - 1;
            int cx = xq + j - 1;
            bool ok = (cy >= 0) & (cy < HH) & (cx >= 0) & (cx < WW);
            p[i * 3 + j] = ok ? disp4[(size_t)b * HW + (size_t)cy * WW + cx] : 0.f;
        }
    }

    const float* sp = spg + ((size_t)b * 9 * FH + (size_t)y) * FW + xq * 4;
    float s[9][4];
#pragma unroll
    for (int c = 0; c < 9; ++c) {
        vf4 v = __builtin_nontemporal_load(
            reinterpret_cast<const vf4*>(sp + (size_t)c * FHW));
        s[c][0] = v.x; s[c][1] = v.y; s[c][2] = v.z; s[c][3] = v.w;
    }

    vf4 ov;
#pragma unroll
    for (int k = 0; k < 4; ++k) {
        float m = s[0][k];
#pragma unroll
        for (int c = 1; c < 9; ++c) m = fmaxf(m, s[c][k]);
        float num = 0.f, den = 0.f;
#pragma unroll
        for (int c = 0; c < 9; ++c) {
            float e = __expf(s[c][k] - m);
            num = fmaf(e, p[c], num);
            den += e;
        }
        ov[k] = 4.f * __fdividef(num, den);
    }

    __builtin_nontemporal_store(ov, reinterpret_cast<vf4*>(
        out + ((size_t)b * FH + (size_t)y) * FW + xq * 4));
}

extern "C" void kernel_launch(void* const* d_in, const int* in_sizes, int n_in,
                              void* d_out, int out_size, void* d_ws, size_t ws_size,
                              hipStream_t stream) {
    const float* cost = (const float*)d_in[0];
    const float* spg  = (const float*)d_in[1];
    float* outp  = (float*)d_out;
    float* disp4 = (float*)d_ws;           // needs BB*HH*WW*4 = 3.93 MB

    {
        int total = BB * HH * (WW / 4);    // 61440
        int blocks = (total + 255) / 256;  // 240 -> 1 block per CU
        disp4_kernel<<<blocks, 256, 0, stream>>>(cost, disp4);
    }
    {
        int total = BB * FH * (FW / 4);    // 983040
        int blocks = (total + 255) / 256;  // 3840 -> exactly 15 blocks/CU
        upfeat_kernel<<<blocks, 256, 0, stream>>>(spg, disp4, outp);
    }
}